// Round 1
// baseline (2089.777 us; speedup 1.0000x reference)
//
#include <hip/hip_runtime.h>
#include <hip/hip_bf16.h>

// ---------------------------------------------------------------------------
// 2-layer GAT on MI355X.
// Pipeline: convert feat->bf16, transpose W1/W2 -> bf16 [N][K],
//   GEMM1 (bf16 MFMA, fp32 out) -> h1[60032][2048]
//   el/er dots, CSR build (hist/scan/scatter), softmax stats,
//   aggregation+bias+relu+head-mean -> outm bf16 [15104][256]
//   GEMM2 -> h2[15104][128], el2/er2, CSR2, stats2, aggregation2 -> d_out.
// Workspace need ~767 MB.
// ---------------------------------------------------------------------------

typedef __bf16 bf16;
typedef bf16 bf16x8 __attribute__((ext_vector_type(8)));
typedef float f32x4 __attribute__((ext_vector_type(4)));

#define N_SRC0V 60000
#define N_DST0V 15000
#define N_DST1V 4000
#define E0V 240000
#define E1V 64000
#define HD1V 2048
#define K1V 2048
#define M1PAD 60032
#define M2PAD 15104

#define BM 128
#define BN 128
#define BK 64

__device__ __forceinline__ void gload16(const void* g, void* l) {
  __builtin_amdgcn_global_load_lds(
      (__attribute__((address_space(1))) void*)(g),
      (__attribute__((address_space(3))) void*)(l), 16, 0, 0);
}

// ---------------- feat fp32 -> bf16, 8 elems/thread ----------------
__global__ void k_convert(const float* __restrict__ x, bf16* __restrict__ y, long n8) {
  long i = (long)blockIdx.x * 256 + threadIdx.x;
  if (i >= n8) return;
  const float4* xp = (const float4*)(x + i * 8);
  float4 a = xp[0], b = xp[1];
  bf16x8 o;
  o[0] = (bf16)a.x; o[1] = (bf16)a.y; o[2] = (bf16)a.z; o[3] = (bf16)a.w;
  o[4] = (bf16)b.x; o[5] = (bf16)b.y; o[6] = (bf16)b.z; o[7] = (bf16)b.w;
  *(bf16x8*)(y + i * 8) = o;
}

// ---------------- W[R][C] fp32 -> WT[C][R] bf16 ----------------
__global__ void k_transpose_bf16(const float* __restrict__ W, bf16* __restrict__ WT,
                                 int R, int C) {
  __shared__ float tile[32][33];
  int tx = threadIdx.x & 31, ty = threadIdx.x >> 5;
  int c0 = blockIdx.x * 32, r0 = blockIdx.y * 32;
  for (int i = ty; i < 32; i += 8) {
    int r = r0 + i, c = c0 + tx;
    tile[i][tx] = (r < R && c < C) ? W[(size_t)r * C + c] : 0.f;
  }
  __syncthreads();
  for (int i = ty; i < 32; i += 8) {
    int c = c0 + i, r = r0 + tx;
    if (c < C && r < R) WT[(size_t)c * R + r] = (bf16)tile[tx][i];
  }
}

// ---------------- bf16 GEMM: C[M][N] = A[M][K] * BT[N][K]^T (fp32 out) -----
// m97 structure: 128x128 block tile, 4 waves in 2x2, 64x64 per wave,
// global_load_lds width-16 staging, 16x16x32 bf16 MFMA.
__global__ __launch_bounds__(256) void k_gemm_bt(
    const bf16* __restrict__ A, const bf16* __restrict__ BT,
    float* __restrict__ C, int N, int K) {
  __shared__ bf16 sA[BM * BK];
  __shared__ bf16 sB[BN * BK];
  const int tid = threadIdx.x;
  const int lane = tid & 63;
  const int wv = tid >> 6;
  const int wm = wv >> 1, wn = wv & 1;
  const int lr = lane & 15, lq = lane >> 4;
  const int m0 = blockIdx.y * BM;
  const int n0 = blockIdx.x * BN;

  const f32x4 vzero = {0.f, 0.f, 0.f, 0.f};
  f32x4 acc[4][4];
#pragma unroll
  for (int i = 0; i < 4; ++i)
#pragma unroll
    for (int j = 0; j < 4; ++j) acc[i][j] = vzero;

  for (int k0 = 0; k0 < K; k0 += BK) {
#pragma unroll
    for (int it = 0; it < 4; ++it) {
      int c = it * 256 + tid;
      int row = c >> 3, kc = (c & 7) << 3;
      gload16(A + (size_t)(m0 + row) * K + k0 + kc, &sA[c * 8]);
      gload16(BT + (size_t)(n0 + row) * K + k0 + kc, &sB[c * 8]);
    }
    __syncthreads();
#pragma unroll
    for (int kk = 0; kk < BK; kk += 32) {
      bf16x8 af[4], bfr[4];
#pragma unroll
      for (int i = 0; i < 4; ++i)
        af[i] = *(const bf16x8*)&sA[(wm * 64 + i * 16 + lr) * BK + kk + lq * 8];
#pragma unroll
      for (int j = 0; j < 4; ++j)
        bfr[j] = *(const bf16x8*)&sB[(wn * 64 + j * 16 + lr) * BK + kk + lq * 8];
#pragma unroll
      for (int i = 0; i < 4; ++i)
#pragma unroll
        for (int j = 0; j < 4; ++j)
          acc[i][j] = __builtin_amdgcn_mfma_f32_16x16x32_bf16(af[i], bfr[j], acc[i][j], 0, 0, 0);
    }
    __syncthreads();
  }
  // epilogue: D row=(lane>>4)*4+reg, col=lane&15  [m89/m91-verified layout]
#pragma unroll
  for (int i = 0; i < 4; ++i)
#pragma unroll
    for (int j = 0; j < 4; ++j) {
      int row = m0 + wm * 64 + i * 16 + lq * 4;
      int col = n0 + wn * 64 + j * 16 + lr;
#pragma unroll
      for (int r = 0; r < 4; ++r)
        C[(size_t)(row + r) * N + col] = acc[i][j][r];
    }
}

// ---------------- el/er = sum_d h[row,h,d]*al/ar[h,d] ----------------
__global__ void k_el_er(const float* __restrict__ h, const float* __restrict__ al,
                        const float* __restrict__ ar, float* __restrict__ el,
                        float* __restrict__ er, int H, int D, int n_dst) {
  int row = blockIdx.x;
  int t = threadIdx.x;
  int TPH = 256 / H;
  int head = t / TPH, j = t % TPH;
  int HD = H * D;
  __shared__ float rl[256], rr[256];
  float pl = 0.f, pr = 0.f;
  for (int d = j; d < D; d += TPH) {
    float v = h[(size_t)row * HD + head * D + d];
    pl += v * al[head * D + d];
    pr += v * ar[head * D + d];
  }
  rl[t] = pl; rr[t] = pr;
  __syncthreads();
  for (int s = TPH >> 1; s > 0; s >>= 1) {
    if (j < s) { rl[t] += rl[t + s]; rr[t] += rr[t + s]; }
    __syncthreads();
  }
  if (j == 0) {
    el[(size_t)row * H + head] = rl[t];
    if (row < n_dst) er[(size_t)row * H + head] = rr[t];
  }
}

// ---------------- CSR build ----------------
__global__ void k_zero(int* __restrict__ p, int n) {
  int i = blockIdx.x * 256 + threadIdx.x;
  if (i < n) p[i] = 0;
}
__global__ void k_hist(const int* __restrict__ d, int E, int* __restrict__ counts) {
  int e = blockIdx.x * 256 + threadIdx.x;
  if (e < E) atomicAdd(&counts[d[e]], 1);
}
__global__ void k_scan(const int* __restrict__ counts, int n, int* __restrict__ offs,
                       int* __restrict__ cursor) {
  __shared__ int part[1024];
  int t = threadIdx.x;
  int per = (n + 1023) >> 10;
  int b = t * per;
  int e = b + per < n ? b + per : n;
  int s = 0;
  for (int i = b; i < e; ++i) s += counts[i];
  part[t] = s;
  __syncthreads();
  for (int off = 1; off < 1024; off <<= 1) {
    int v = 0;
    if (t >= off) v = part[t - off];
    __syncthreads();
    part[t] += v;
    __syncthreads();
  }
  int run = (t == 0) ? 0 : part[t - 1];
  for (int i = b; i < e; ++i) { offs[i] = run; cursor[i] = run; run += counts[i]; }
  if (t == 1023) offs[n] = run;
}
__global__ void k_scatter(const int* __restrict__ d, int E, int* __restrict__ cursor,
                          int* __restrict__ eperm) {
  int e = blockIdx.x * 256 + threadIdx.x;
  if (e < E) eperm[atomicAdd(&cursor[d[e]], 1)] = e;
}

// ---------------- per-(dst,head) softmax max/denominator ----------------
__global__ void k_stats(const int* __restrict__ offs, const int* __restrict__ eperm,
                        const int* __restrict__ srcv, const float* __restrict__ el,
                        const float* __restrict__ er, int n_dst, int H,
                        float* __restrict__ emax, float* __restrict__ eden) {
  int idx = blockIdx.x * 256 + threadIdx.x;
  if (idx >= n_dst * H) return;
  int dn = idx / H, hh = idx - dn * H;
  int s0 = offs[dn], s1 = offs[dn + 1];
  float erv = er[idx];
  float mx = -1e30f;
  for (int p = s0; p < s1; ++p) {
    float v = el[srcv[eperm[p]] * H + hh] + erv;
    v = v > 0.f ? v : 0.2f * v;
    mx = fmaxf(mx, v);
  }
  if (s1 == s0) mx = 0.f;  // zero in-degree guard (matches isfinite guard)
  float s = 0.f;
  for (int p = s0; p < s1; ++p) {
    float v = el[srcv[eperm[p]] * H + hh] + erv;
    v = v > 0.f ? v : 0.2f * v;
    s += expf(v - mx);
  }
  emax[idx] = mx;
  eden[idx] = s;
}

// ---------------- layer1 aggregation + bias + relu + head-mean ----------------
__global__ __launch_bounds__(256) void k_aggr1(
    const int* __restrict__ offs, const int* __restrict__ eperm,
    const int* __restrict__ srcv, const float* __restrict__ el,
    const float* __restrict__ er, const float* __restrict__ emax,
    const float* __restrict__ eden, const float* __restrict__ h1,
    const float* __restrict__ b1, bf16* __restrict__ outm) {
  int dn = blockIdx.x;
  int t = threadIdx.x;
  int head = t >> 5;          // 8 heads x 32 threads
  int jd = (t & 31) << 3;     // 8 contiguous d per thread
  __shared__ float wbuf[32][8];
  __shared__ int sidx[32];
  __shared__ float obuf[2048];
  float acc[8] = {0.f, 0.f, 0.f, 0.f, 0.f, 0.f, 0.f, 0.f};
  int s0 = offs[dn], s1 = offs[dn + 1];
  for (int base = s0; base < s1; base += 32) {
    int rem = s1 - base;
    int cnt = rem < 32 ? rem : 32;
    __syncthreads();
    if (t < cnt * 8) {
      int ec = t >> 3, hh = t & 7;
      int e = eperm[base + ec];
      int sv = srcv[e];
      if (hh == 0) sidx[ec] = sv;
      float v = el[sv * 8 + hh] + er[dn * 8 + hh];
      v = v > 0.f ? v : 0.2f * v;
      float den = eden[dn * 8 + hh];
      wbuf[ec][hh] = den > 0.f ? expf(v - emax[dn * 8 + hh]) / den : 0.f;
    }
    __syncthreads();
    for (int ec = 0; ec < cnt; ++ec) {
      float w = wbuf[ec][head];
      const float* hp = h1 + (size_t)sidx[ec] * 2048 + (head << 8) + jd;
      float4 x0 = *(const float4*)hp;
      float4 x1 = *(const float4*)(hp + 4);
      acc[0] += w * x0.x; acc[1] += w * x0.y; acc[2] += w * x0.z; acc[3] += w * x0.w;
      acc[4] += w * x1.x; acc[5] += w * x1.y; acc[6] += w * x1.z; acc[7] += w * x1.w;
    }
  }
  int ob = (head << 8) + jd;
#pragma unroll
  for (int k2 = 0; k2 < 8; ++k2) {
    float v = acc[k2] + b1[ob + k2];
    obuf[ob + k2] = v > 0.f ? v : 0.f;   // relu per head BEFORE mean
  }
  __syncthreads();
  float sum = 0.f;
#pragma unroll
  for (int hh = 0; hh < 8; ++hh) sum += obuf[hh * 256 + t];
  outm[(size_t)dn * 256 + t] = (bf16)(sum * 0.125f);
}

// ---------------- layer2 aggregation + bias (no act) -> d_out ----------------
__global__ __launch_bounds__(128) void k_aggr2(
    const int* __restrict__ offs, const int* __restrict__ eperm,
    const int* __restrict__ srcv, const float* __restrict__ el,
    const float* __restrict__ er, const float* __restrict__ emax,
    const float* __restrict__ eden, const float* __restrict__ h2,
    const float* __restrict__ b2, float* __restrict__ out) {
  int dn = blockIdx.x;
  int t = threadIdx.x;
  __shared__ float wbuf[64];
  __shared__ int sidx[64];
  float acc = 0.f;
  int s0 = offs[dn], s1 = offs[dn + 1];
  float erv = er[dn], mx = emax[dn], den = eden[dn];
  for (int base = s0; base < s1; base += 64) {
    int rem = s1 - base;
    int cnt = rem < 64 ? rem : 64;
    __syncthreads();
    if (t < cnt) {
      int e = eperm[base + t];
      int sv = srcv[e];
      sidx[t] = sv;
      float v = el[sv] + erv;
      v = v > 0.f ? v : 0.2f * v;
      wbuf[t] = den > 0.f ? expf(v - mx) / den : 0.f;
    }
    __syncthreads();
    for (int ec = 0; ec < cnt; ++ec)
      acc += wbuf[ec] * h2[(size_t)sidx[ec] * 128 + t];
  }
  out[(size_t)dn * 128 + t] = acc + b2[t];
}

// ---------------------------------------------------------------------------
extern "C" void kernel_launch(void* const* d_in, const int* in_sizes, int n_in,
                              void* d_out, int out_size, void* d_ws, size_t ws_size,
                              hipStream_t stream) {
  const float* feat = (const float*)d_in[0];
  const float* W1   = (const float*)d_in[1];
  const float* al1  = (const float*)d_in[2];
  const float* ar1  = (const float*)d_in[3];
  const float* b1   = (const float*)d_in[4];
  const float* W2   = (const float*)d_in[5];
  const float* al2  = (const float*)d_in[6];
  const float* ar2  = (const float*)d_in[7];
  const float* b2   = (const float*)d_in[8];
  const int* src0   = (const int*)d_in[9];
  const int* dst0   = (const int*)d_in[10];
  const int* src1   = (const int*)d_in[11];
  const int* dst1   = (const int*)d_in[12];
  float* out = (float*)d_out;

  // ---- workspace carve ----
  char* w = (char*)d_ws;
  auto alloc = [&](size_t bytes) {
    char* p = w;
    w += (bytes + 255) & ~(size_t)255;
    return p;
  };
  bf16*  featb   = (bf16*)alloc((size_t)M1PAD * K1V * 2);     // 245.9 MB
  bf16*  w1t     = (bf16*)alloc((size_t)HD1V * K1V * 2);      // 8.4 MB
  bf16*  w2t     = (bf16*)alloc((size_t)128 * 256 * 2);
  float* h1      = (float*)alloc((size_t)M1PAD * HD1V * 4);   // 491.8 MB
  float* el1     = (float*)alloc((size_t)N_SRC0V * 8 * 4);
  float* er1     = (float*)alloc((size_t)N_DST0V * 8 * 4);
  float* emax1   = (float*)alloc((size_t)N_DST0V * 8 * 4);
  float* eden1   = (float*)alloc((size_t)N_DST0V * 8 * 4);
  bf16*  outm    = (bf16*)alloc((size_t)M2PAD * 256 * 2);
  float* h2      = (float*)alloc((size_t)M2PAD * 128 * 4);
  float* el2     = (float*)alloc((size_t)N_DST0V * 4);
  float* er2     = (float*)alloc((size_t)N_DST1V * 4);
  float* emax2   = (float*)alloc((size_t)N_DST1V * 4);
  float* eden2   = (float*)alloc((size_t)N_DST1V * 4);
  int*   counts1 = (int*)alloc((size_t)N_DST0V * 4);
  int*   offs1   = (int*)alloc((size_t)(N_DST0V + 1) * 4);
  int*   cursor1 = (int*)alloc((size_t)N_DST0V * 4);
  int*   eperm1  = (int*)alloc((size_t)E0V * 4);
  int*   counts2 = (int*)alloc((size_t)N_DST1V * 4);
  int*   offs2   = (int*)alloc((size_t)(N_DST1V + 1) * 4);
  int*   cursor2 = (int*)alloc((size_t)N_DST1V * 4);
  int*   eperm2  = (int*)alloc((size_t)E1V * 4);

  // ---- prep: zero counts, convert feat, transpose weights ----
  k_zero<<<(N_DST0V + 255) / 256, 256, 0, stream>>>(counts1, N_DST0V);
  k_zero<<<(N_DST1V + 255) / 256, 256, 0, stream>>>(counts2, N_DST1V);
  {
    long n8 = (long)N_SRC0V * K1V / 8;  // pad rows left as poison: never read
    k_convert<<<(unsigned)((n8 + 255) / 256), 256, 0, stream>>>(feat, featb, n8);
  }
  k_transpose_bf16<<<dim3(64, 64), 256, 0, stream>>>(W1, w1t, K1V, HD1V);
  k_transpose_bf16<<<dim3(4, 8), 256, 0, stream>>>(W2, w2t, 256, 128);

  // ---- layer 1 ----
  k_gemm_bt<<<dim3(HD1V / BN, M1PAD / BM), 256, 0, stream>>>(featb, w1t, h1, HD1V, K1V);
  k_el_er<<<N_SRC0V, 256, 0, stream>>>(h1, al1, ar1, el1, er1, 8, 256, N_DST0V);
  k_hist<<<(E0V + 255) / 256, 256, 0, stream>>>(dst0, E0V, counts1);
  k_scan<<<1, 1024, 0, stream>>>(counts1, N_DST0V, offs1, cursor1);
  k_scatter<<<(E0V + 255) / 256, 256, 0, stream>>>(dst0, E0V, cursor1, eperm1);
  k_stats<<<(N_DST0V * 8 + 255) / 256, 256, 0, stream>>>(offs1, eperm1, src0, el1, er1,
                                                         N_DST0V, 8, emax1, eden1);
  k_aggr1<<<N_DST0V, 256, 0, stream>>>(offs1, eperm1, src0, el1, er1, emax1, eden1,
                                       h1, b1, outm);

  // ---- layer 2 ----
  k_gemm_bt<<<dim3(1, M2PAD / BM), 256, 0, stream>>>(outm, w2t, h2, 128, 256);
  k_el_er<<<N_DST0V, 256, 0, stream>>>(h2, al2, ar2, el2, er2, 1, 128, N_DST1V);
  k_hist<<<(E1V + 255) / 256, 256, 0, stream>>>(dst1, E1V, counts2);
  k_scan<<<1, 1024, 0, stream>>>(counts2, N_DST1V, offs2, cursor2);
  k_scatter<<<(E1V + 255) / 256, 256, 0, stream>>>(dst1, E1V, cursor2, eperm2);
  k_stats<<<(N_DST1V + 255) / 256, 256, 0, stream>>>(offs2, eperm2, src1, el2, er2,
                                                     N_DST1V, 1, emax2, eden2);
  k_aggr2<<<N_DST1V, 128, 0, stream>>>(offs2, eperm2, src1, el2, er2, emax2, eden2,
                                       h2, b2, out);
}

// Round 2
// 1982.154 us; speedup vs baseline: 1.0543x; 1.0543x over previous
//
#include <hip/hip_runtime.h>
#include <hip/hip_bf16.h>

// ---------------------------------------------------------------------------
// 2-layer GAT on MI355X.
// R1 -> R2 changes:
//  * GEMM LDS tiles stored in MFMA-fragment order (lane-linear) -> zero bank
//    conflicts (was 1.84e8 conflict cycles with row-major 128B-stride layout).
//  * h1 stored as bf16 (halves GEMM1 write + el/er read + aggr1 gather BW).
//  * el/er kernels vectorized (bf16x8 / float4 + shfl reductions).
// ---------------------------------------------------------------------------

typedef __bf16 bf16;
typedef bf16 bf16x8 __attribute__((ext_vector_type(8)));
typedef float f32x4 __attribute__((ext_vector_type(4)));

#define N_SRC0V 60000
#define N_DST0V 15000
#define N_DST1V 4000
#define E0V 240000
#define E1V 64000
#define HD1V 2048
#define K1V 2048
#define M1PAD 60032
#define M2PAD 15104

#define BM 128
#define BN 128
#define BK 64

__device__ __forceinline__ void gload16(const void* g, void* l) {
  __builtin_amdgcn_global_load_lds(
      (__attribute__((address_space(1))) void*)(g),
      (__attribute__((address_space(3))) void*)(l), 16, 0, 0);
}

// ---------------- feat fp32 -> bf16, 8 elems/thread ----------------
__global__ void k_convert(const float* __restrict__ x, bf16* __restrict__ y, long n8) {
  long i = (long)blockIdx.x * 256 + threadIdx.x;
  if (i >= n8) return;
  const float4* xp = (const float4*)(x + i * 8);
  float4 a = xp[0], b = xp[1];
  bf16x8 o;
  o[0] = (bf16)a.x; o[1] = (bf16)a.y; o[2] = (bf16)a.z; o[3] = (bf16)a.w;
  o[4] = (bf16)b.x; o[5] = (bf16)b.y; o[6] = (bf16)b.z; o[7] = (bf16)b.w;
  *(bf16x8*)(y + i * 8) = o;
}

// ---------------- W[R][C] fp32 -> WT[C][R] bf16 ----------------
__global__ void k_transpose_bf16(const float* __restrict__ W, bf16* __restrict__ WT,
                                 int R, int C) {
  __shared__ float tile[32][33];
  int tx = threadIdx.x & 31, ty = threadIdx.x >> 5;
  int c0 = blockIdx.x * 32, r0 = blockIdx.y * 32;
  for (int i = ty; i < 32; i += 8) {
    int r = r0 + i, c = c0 + tx;
    tile[i][tx] = (r < R && c < C) ? W[(size_t)r * C + c] : 0.f;
  }
  __syncthreads();
  for (int i = ty; i < 32; i += 8) {
    int c = c0 + i, r = r0 + tx;
    if (c < C && r < R) WT[(size_t)c * R + r] = (bf16)tile[tx][i];
  }
}

// ---------------- bf16 GEMM: C[M][N] = A[M][K] * BT[N][K]^T -----------------
// 128x128 tile, 4 waves 2x2, 64x64/wave, 16x16x32 bf16 MFMA.
// LDS layout = fragment order: 16 segments (seg = rb*2+kb, rb=16-row block,
// kb=32-k block) of 64 lanes x 8 bf16. Lane L of segment holds
// A[rb*16 + (L&15)][kb*32 + (L>>4)*8 .. +7]. All LDS reads/writes are
// base + lane*16B -> conflict-free.
template <typename OutT>
__global__ __launch_bounds__(256) void k_gemm_bt(
    const bf16* __restrict__ A, const bf16* __restrict__ BT,
    OutT* __restrict__ C, int N, int K) {
  __shared__ bf16 sA[BM * BK];
  __shared__ bf16 sB[BN * BK];
  const int tid = threadIdx.x;
  const int lane = tid & 63;
  const int wv = tid >> 6;
  const int wm = wv >> 1, wn = wv & 1;
  const int lr = lane & 15, lq = lane >> 4;
  const int m0 = blockIdx.y * BM;
  const int n0 = blockIdx.x * BN;

  const f32x4 vzero = {0.f, 0.f, 0.f, 0.f};
  f32x4 acc[4][4];
#pragma unroll
  for (int i = 0; i < 4; ++i)
#pragma unroll
    for (int j = 0; j < 4; ++j) acc[i][j] = vzero;

  for (int k0 = 0; k0 < K; k0 += BK) {
#pragma unroll
    for (int it = 0; it < 4; ++it) {
      int c = it * 256 + tid;           // 0..1023
      int seg = c >> 6;                 // wave-uniform (it*4 + wv)
      int ln = c & 63;
      int row = (seg >> 1) * 16 + (ln & 15);
      int col = (seg & 1) * 32 + (ln >> 4) * 8;
      gload16(A + (size_t)(m0 + row) * K + k0 + col, &sA[c * 8]);
      gload16(BT + (size_t)(n0 + row) * K + k0 + col, &sB[c * 8]);
    }
    __syncthreads();
#pragma unroll
    for (int kk = 0; kk < BK; kk += 32) {
      const int kb = kk >> 5;
      bf16x8 af[4], bfr[4];
#pragma unroll
      for (int i = 0; i < 4; ++i)
        af[i] = *(const bf16x8*)&sA[(((wm * 4 + i) * 2 + kb) * 64 + lane) * 8];
#pragma unroll
      for (int j = 0; j < 4; ++j)
        bfr[j] = *(const bf16x8*)&sB[(((wn * 4 + j) * 2 + kb) * 64 + lane) * 8];
#pragma unroll
      for (int i = 0; i < 4; ++i)
#pragma unroll
        for (int j = 0; j < 4; ++j)
          acc[i][j] = __builtin_amdgcn_mfma_f32_16x16x32_bf16(af[i], bfr[j], acc[i][j], 0, 0, 0);
    }
    __syncthreads();
  }
  // epilogue: D row=(lane>>4)*4+reg, col=lane&15  [m89/m91-verified layout]
#pragma unroll
  for (int i = 0; i < 4; ++i)
#pragma unroll
    for (int j = 0; j < 4; ++j) {
      int row = m0 + wm * 64 + i * 16 + lq * 4;
      int col = n0 + wn * 64 + j * 16 + lr;
#pragma unroll
      for (int r = 0; r < 4; ++r)
        C[(size_t)(row + r) * N + col] = (OutT)acc[i][j][r];
    }
}

// ---------------- layer1 el/er: h bf16 [row][2048], 8 heads x 256 ----------
__global__ void k_el_er1(const bf16* __restrict__ h, const float* __restrict__ al,
                         const float* __restrict__ ar, float* __restrict__ el,
                         float* __restrict__ er, int n_dst) {
  int row = blockIdx.x;
  int t = threadIdx.x;               // head = t>>5, 32 threads/head, 8 d each
  bf16x8 hv = *(const bf16x8*)(h + (size_t)row * 2048 + t * 8);
  float pl = 0.f, pr = 0.f;
#pragma unroll
  for (int e = 0; e < 8; ++e) {
    float v = (float)hv[e];
    pl += v * al[t * 8 + e];
    pr += v * ar[t * 8 + e];
  }
#pragma unroll
  for (int off = 16; off >= 1; off >>= 1) {
    pl += __shfl_down(pl, off);
    pr += __shfl_down(pr, off);
  }
  if ((t & 31) == 0) {
    el[(size_t)row * 8 + (t >> 5)] = pl;
    if (row < n_dst) er[(size_t)row * 8 + (t >> 5)] = pr;
  }
}

// ---------------- layer2 el/er: h fp32 [row][128], 1 head ----------------
__global__ void k_el_er2(const float* __restrict__ h, const float* __restrict__ al,
                         const float* __restrict__ ar, float* __restrict__ el,
                         float* __restrict__ er, int n_el, int n_dst) {
  int t = threadIdx.x;
  int row = blockIdx.x * 16 + (t >> 4);   // 16 rows/block, 16 threads/row
  int s = t & 15;
  const float* hp = h + (size_t)row * 128 + s * 8;
  float4 a = *(const float4*)hp;
  float4 b = *(const float4*)(hp + 4);
  float pl = a.x * al[s * 8] + a.y * al[s * 8 + 1] + a.z * al[s * 8 + 2] + a.w * al[s * 8 + 3]
           + b.x * al[s * 8 + 4] + b.y * al[s * 8 + 5] + b.z * al[s * 8 + 6] + b.w * al[s * 8 + 7];
  float pr = a.x * ar[s * 8] + a.y * ar[s * 8 + 1] + a.z * ar[s * 8 + 2] + a.w * ar[s * 8 + 3]
           + b.x * ar[s * 8 + 4] + b.y * ar[s * 8 + 5] + b.z * ar[s * 8 + 6] + b.w * ar[s * 8 + 7];
#pragma unroll
  for (int off = 8; off >= 1; off >>= 1) {
    pl += __shfl_down(pl, off);
    pr += __shfl_down(pr, off);
  }
  if (s == 0 && row < n_el) {
    el[row] = pl;
    if (row < n_dst) er[row] = pr;
  }
}

// ---------------- CSR build ----------------
__global__ void k_zero(int* __restrict__ p, int n) {
  int i = blockIdx.x * 256 + threadIdx.x;
  if (i < n) p[i] = 0;
}
__global__ void k_hist(const int* __restrict__ d, int E, int* __restrict__ counts) {
  int e = blockIdx.x * 256 + threadIdx.x;
  if (e < E) atomicAdd(&counts[d[e]], 1);
}
__global__ void k_scan(const int* __restrict__ counts, int n, int* __restrict__ offs,
                       int* __restrict__ cursor) {
  __shared__ int part[1024];
  int t = threadIdx.x;
  int per = (n + 1023) >> 10;
  int b = t * per;
  int e = b + per < n ? b + per : n;
  int s = 0;
  for (int i = b; i < e; ++i) s += counts[i];
  part[t] = s;
  __syncthreads();
  for (int off = 1; off < 1024; off <<= 1) {
    int v = 0;
    if (t >= off) v = part[t - off];
    __syncthreads();
    part[t] += v;
    __syncthreads();
  }
  int run = (t == 0) ? 0 : part[t - 1];
  for (int i = b; i < e; ++i) { offs[i] = run; cursor[i] = run; run += counts[i]; }
  if (t == 1023) offs[n] = run;
}
__global__ void k_scatter(const int* __restrict__ d, int E, int* __restrict__ cursor,
                          int* __restrict__ eperm) {
  int e = blockIdx.x * 256 + threadIdx.x;
  if (e < E) eperm[atomicAdd(&cursor[d[e]], 1)] = e;
}

// ---------------- per-(dst,head) softmax max/denominator ----------------
__global__ void k_stats(const int* __restrict__ offs, const int* __restrict__ eperm,
                        const int* __restrict__ srcv, const float* __restrict__ el,
                        const float* __restrict__ er, int n_dst, int H,
                        float* __restrict__ emax, float* __restrict__ eden) {
  int idx = blockIdx.x * 256 + threadIdx.x;
  if (idx >= n_dst * H) return;
  int dn = idx / H, hh = idx - dn * H;
  int s0 = offs[dn], s1 = offs[dn + 1];
  float erv = er[idx];
  float mx = -1e30f;
  for (int p = s0; p < s1; ++p) {
    float v = el[srcv[eperm[p]] * H + hh] + erv;
    v = v > 0.f ? v : 0.2f * v;
    mx = fmaxf(mx, v);
  }
  if (s1 == s0) mx = 0.f;  // zero in-degree guard (matches isfinite guard)
  float s = 0.f;
  for (int p = s0; p < s1; ++p) {
    float v = el[srcv[eperm[p]] * H + hh] + erv;
    v = v > 0.f ? v : 0.2f * v;
    s += expf(v - mx);
  }
  emax[idx] = mx;
  eden[idx] = s;
}

// ---------------- layer1 aggregation + bias + relu + head-mean ----------------
__global__ __launch_bounds__(256) void k_aggr1(
    const int* __restrict__ offs, const int* __restrict__ eperm,
    const int* __restrict__ srcv, const float* __restrict__ el,
    const float* __restrict__ er, const float* __restrict__ emax,
    const float* __restrict__ eden, const bf16* __restrict__ h1,
    const float* __restrict__ b1, bf16* __restrict__ outm) {
  int dn = blockIdx.x;
  int t = threadIdx.x;
  int head = t >> 5;          // 8 heads x 32 threads
  int jd = (t & 31) << 3;     // 8 contiguous d per thread
  __shared__ float wbuf[32][8];
  __shared__ int sidx[32];
  __shared__ float obuf[2048];
  float acc[8] = {0.f, 0.f, 0.f, 0.f, 0.f, 0.f, 0.f, 0.f};
  int s0 = offs[dn], s1 = offs[dn + 1];
  for (int base = s0; base < s1; base += 32) {
    int rem = s1 - base;
    int cnt = rem < 32 ? rem : 32;
    __syncthreads();
    if (t < cnt * 8) {
      int ec = t >> 3, hh = t & 7;
      int e = eperm[base + ec];
      int sv = srcv[e];
      if (hh == 0) sidx[ec] = sv;
      float v = el[sv * 8 + hh] + er[dn * 8 + hh];
      v = v > 0.f ? v : 0.2f * v;
      float den = eden[dn * 8 + hh];
      wbuf[ec][hh] = den > 0.f ? expf(v - emax[dn * 8 + hh]) / den : 0.f;
    }
    __syncthreads();
    for (int ec = 0; ec < cnt; ++ec) {
      float w = wbuf[ec][head];
      const bf16* hp = h1 + (size_t)sidx[ec] * 2048 + (head << 8) + jd;
      bf16x8 x = *(const bf16x8*)hp;
#pragma unroll
      for (int e2 = 0; e2 < 8; ++e2) acc[e2] += w * (float)x[e2];
    }
  }
  int ob = (head << 8) + jd;
#pragma unroll
  for (int k2 = 0; k2 < 8; ++k2) {
    float v = acc[k2] + b1[ob + k2];
    obuf[ob + k2] = v > 0.f ? v : 0.f;   // relu per head BEFORE mean
  }
  __syncthreads();
  float sum = 0.f;
#pragma unroll
  for (int hh = 0; hh < 8; ++hh) sum += obuf[hh * 256 + t];
  outm[(size_t)dn * 256 + t] = (bf16)(sum * 0.125f);
}

// ---------------- layer2 aggregation + bias (no act) -> d_out ----------------
__global__ __launch_bounds__(128) void k_aggr2(
    const int* __restrict__ offs, const int* __restrict__ eperm,
    const int* __restrict__ srcv, const float* __restrict__ el,
    const float* __restrict__ er, const float* __restrict__ emax,
    const float* __restrict__ eden, const float* __restrict__ h2,
    const float* __restrict__ b2, float* __restrict__ out) {
  int dn = blockIdx.x;
  int t = threadIdx.x;
  __shared__ float wbuf[64];
  __shared__ int sidx[64];
  float acc = 0.f;
  int s0 = offs[dn], s1 = offs[dn + 1];
  float erv = er[dn], mx = emax[dn], den = eden[dn];
  for (int base = s0; base < s1; base += 64) {
    int rem = s1 - base;
    int cnt = rem < 64 ? rem : 64;
    __syncthreads();
    if (t < cnt) {
      int e = eperm[base + t];
      int sv = srcv[e];
      sidx[t] = sv;
      float v = el[sv] + erv;
      v = v > 0.f ? v : 0.2f * v;
      wbuf[t] = den > 0.f ? expf(v - mx) / den : 0.f;
    }
    __syncthreads();
    for (int ec = 0; ec < cnt; ++ec)
      acc += wbuf[ec] * h2[(size_t)sidx[ec] * 128 + t];
  }
  out[(size_t)dn * 128 + t] = acc + b2[t];
}

// ---------------------------------------------------------------------------
extern "C" void kernel_launch(void* const* d_in, const int* in_sizes, int n_in,
                              void* d_out, int out_size, void* d_ws, size_t ws_size,
                              hipStream_t stream) {
  const float* feat = (const float*)d_in[0];
  const float* W1   = (const float*)d_in[1];
  const float* al1  = (const float*)d_in[2];
  const float* ar1  = (const float*)d_in[3];
  const float* b1   = (const float*)d_in[4];
  const float* W2   = (const float*)d_in[5];
  const float* al2  = (const float*)d_in[6];
  const float* ar2  = (const float*)d_in[7];
  const float* b2   = (const float*)d_in[8];
  const int* src0   = (const int*)d_in[9];
  const int* dst0   = (const int*)d_in[10];
  const int* src1   = (const int*)d_in[11];
  const int* dst1   = (const int*)d_in[12];
  float* out = (float*)d_out;

  // ---- workspace carve ----
  char* w = (char*)d_ws;
  auto alloc = [&](size_t bytes) {
    char* p = w;
    w += (bytes + 255) & ~(size_t)255;
    return p;
  };
  bf16*  featb   = (bf16*)alloc((size_t)M1PAD * K1V * 2);     // 245.9 MB
  bf16*  w1t     = (bf16*)alloc((size_t)HD1V * K1V * 2);      // 8.4 MB
  bf16*  w2t     = (bf16*)alloc((size_t)128 * 256 * 2);
  bf16*  h1      = (bf16*)alloc((size_t)M1PAD * HD1V * 2);    // 245.9 MB (bf16 now)
  float* el1     = (float*)alloc((size_t)N_SRC0V * 8 * 4);
  float* er1     = (float*)alloc((size_t)N_DST0V * 8 * 4);
  float* emax1   = (float*)alloc((size_t)N_DST0V * 8 * 4);
  float* eden1   = (float*)alloc((size_t)N_DST0V * 8 * 4);
  bf16*  outm    = (bf16*)alloc((size_t)M2PAD * 256 * 2);
  float* h2      = (float*)alloc((size_t)M2PAD * 128 * 4);
  float* el2     = (float*)alloc((size_t)N_DST0V * 4);
  float* er2     = (float*)alloc((size_t)N_DST1V * 4);
  float* emax2   = (float*)alloc((size_t)N_DST1V * 4);
  float* eden2   = (float*)alloc((size_t)N_DST1V * 4);
  int*   counts1 = (int*)alloc((size_t)N_DST0V * 4);
  int*   offs1   = (int*)alloc((size_t)(N_DST0V + 1) * 4);
  int*   cursor1 = (int*)alloc((size_t)N_DST0V * 4);
  int*   eperm1  = (int*)alloc((size_t)E0V * 4);
  int*   counts2 = (int*)alloc((size_t)N_DST1V * 4);
  int*   offs2   = (int*)alloc((size_t)(N_DST1V + 1) * 4);
  int*   cursor2 = (int*)alloc((size_t)N_DST1V * 4);
  int*   eperm2  = (int*)alloc((size_t)E1V * 4);

  // ---- prep: zero counts, convert feat, transpose weights ----
  k_zero<<<(N_DST0V + 255) / 256, 256, 0, stream>>>(counts1, N_DST0V);
  k_zero<<<(N_DST1V + 255) / 256, 256, 0, stream>>>(counts2, N_DST1V);
  {
    long n8 = (long)N_SRC0V * K1V / 8;  // pad rows left as poison: never read
    k_convert<<<(unsigned)((n8 + 255) / 256), 256, 0, stream>>>(feat, featb, n8);
  }
  k_transpose_bf16<<<dim3(64, 64), 256, 0, stream>>>(W1, w1t, K1V, HD1V);
  k_transpose_bf16<<<dim3(4, 8), 256, 0, stream>>>(W2, w2t, 256, 128);

  // ---- layer 1 ----
  k_gemm_bt<bf16><<<dim3(HD1V / BN, M1PAD / BM), 256, 0, stream>>>(featb, w1t, h1, HD1V, K1V);
  k_el_er1<<<N_SRC0V, 256, 0, stream>>>(h1, al1, ar1, el1, er1, N_DST0V);
  k_hist<<<(E0V + 255) / 256, 256, 0, stream>>>(dst0, E0V, counts1);
  k_scan<<<1, 1024, 0, stream>>>(counts1, N_DST0V, offs1, cursor1);
  k_scatter<<<(E0V + 255) / 256, 256, 0, stream>>>(dst0, E0V, cursor1, eperm1);
  k_stats<<<(N_DST0V * 8 + 255) / 256, 256, 0, stream>>>(offs1, eperm1, src0, el1, er1,
                                                         N_DST0V, 8, emax1, eden1);
  k_aggr1<<<N_DST0V, 256, 0, stream>>>(offs1, eperm1, src0, el1, er1, emax1, eden1,
                                       h1, b1, outm);

  // ---- layer 2 ----
  k_gemm_bt<float><<<dim3(1, M2PAD / BM), 256, 0, stream>>>(outm, w2t, h2, 128, 256);
  k_el_er2<<<M2PAD / 16, 256, 0, stream>>>(h2, al2, ar2, el2, er2, N_DST0V, N_DST1V);
  k_hist<<<(E1V + 255) / 256, 256, 0, stream>>>(dst1, E1V, counts2);
  k_scan<<<1, 1024, 0, stream>>>(counts2, N_DST1V, offs2, cursor2);
  k_scatter<<<(E1V + 255) / 256, 256, 0, stream>>>(dst1, E1V, cursor2, eperm2);
  k_stats<<<(N_DST1V + 255) / 256, 256, 0, stream>>>(offs2, eperm2, src1, el2, er2,
                                                     N_DST1V, 1, emax2, eden2);
  k_aggr2<<<N_DST1V, 128, 0, stream>>>(offs2, eperm2, src1, el2, er2, emax2, eden2,
                                       h2, b2, out);
}